// Round 1
// baseline (1342.784 us; speedup 1.0000x reference)
//
#include <hip/hip_runtime.h>
#include <hip/hip_bf16.h>
#include <math.h>

// Problem constants
#define EE 200
#define RR 480
#define TT 8
#define NN 40000
#define BB 1024

#define TS_M 64
#define TS_N 64
#define TS_K 16

// Generic tiled linear: C[M,N] = A[M,K] @ W[N,K]^T (+ bias)
// MODE 0: C = acc + bias
// MODE 1: C = alpha*(acc + bias) + extra[r*N+c]
// MODE 2: C = (acc + bias) * extra[r*N+c]
// Optional row gather on A: srow = gidx[arow*gstride + goff]
template <int MODE>
__global__ __launch_bounds__(256) void linear_kernel(
    const float* __restrict__ A, const int* __restrict__ gidx, int gstride, int goff,
    const float* __restrict__ W, const float* __restrict__ bias,
    float* __restrict__ C, int M, int N, int K,
    const float* __restrict__ extra, float alpha)
{
    __shared__ float As[TS_K][TS_M];
    __shared__ float Ws[TS_K][TS_N];

    const int bm = blockIdx.y * TS_M;
    const int bn = blockIdx.x * TS_N;
    const int tid = threadIdx.x;
    const int tx = tid & 15;       // 0..15
    const int ty = tid >> 4;       // 0..15
    const int lr = tid >> 2;       // 0..63 (tile row for loads)
    const int lk = (tid & 3) * 4;  // 0,4,8,12

    float acc[4][4] = {};

    const int arow = bm + lr;
    int srow = -1;
    if (arow < M) srow = gidx ? gidx[arow * gstride + goff] : arow;
    const int wrow = bn + lr;

    for (int k0 = 0; k0 < K; k0 += TS_K) {
        const bool fullk = (k0 + TS_K) <= K;
        // A tile
        if (srow >= 0) {
            const float* Ap = A + (size_t)srow * K + k0 + lk;
            if (fullk) {
                float4 v = *(const float4*)Ap;
                As[lk + 0][lr] = v.x; As[lk + 1][lr] = v.y;
                As[lk + 2][lr] = v.z; As[lk + 3][lr] = v.w;
            } else {
                #pragma unroll
                for (int i = 0; i < 4; i++) {
                    int kk = k0 + lk + i;
                    As[lk + i][lr] = (kk < K) ? A[(size_t)srow * K + kk] : 0.0f;
                }
            }
        } else {
            #pragma unroll
            for (int i = 0; i < 4; i++) As[lk + i][lr] = 0.0f;
        }
        // W tile
        if (wrow < N) {
            const float* Wp = W + (size_t)wrow * K + k0 + lk;
            if (fullk) {
                float4 v = *(const float4*)Wp;
                Ws[lk + 0][lr] = v.x; Ws[lk + 1][lr] = v.y;
                Ws[lk + 2][lr] = v.z; Ws[lk + 3][lr] = v.w;
            } else {
                #pragma unroll
                for (int i = 0; i < 4; i++) {
                    int kk = k0 + lk + i;
                    Ws[lk + i][lr] = (kk < K) ? W[(size_t)wrow * K + kk] : 0.0f;
                }
            }
        } else {
            #pragma unroll
            for (int i = 0; i < 4; i++) Ws[lk + i][lr] = 0.0f;
        }
        __syncthreads();

        #pragma unroll
        for (int kk = 0; kk < TS_K; kk++) {
            float a4[4], b4[4];
            *(float4*)a4 = *(const float4*)&As[kk][ty * 4];
            *(float4*)b4 = *(const float4*)&Ws[kk][tx * 4];
            #pragma unroll
            for (int i = 0; i < 4; i++)
                #pragma unroll
                for (int j = 0; j < 4; j++)
                    acc[i][j] += a4[i] * b4[j];
        }
        __syncthreads();
    }

    #pragma unroll
    for (int i = 0; i < 4; i++) {
        int r = bm + ty * 4 + i;
        if (r >= M) continue;
        #pragma unroll
        for (int j = 0; j < 4; j++) {
            int c = bn + tx * 4 + j;
            if (c >= N) continue;
            float v = acc[i][j];
            if (bias) v += bias[c];
            if (MODE == 1) v = alpha * v + extra[(size_t)r * N + c];
            else if (MODE == 2) v = v * extra[(size_t)r * N + c];
            C[(size_t)r * N + c] = v;
        }
    }
}

// Big GEMM + fused sigmoid + path-loss partial accumulation.
__global__ __launch_bounds__(256) void score_kernel(
    const float* __restrict__ A,   // s1h (1024,200)
    const float* __restrict__ P,   // (40000,200)
    const int* __restrict__ triples,
    float* __restrict__ outScore,  // (1024,40000)
    double* __restrict__ accPath,
    int M, int N, int K)
{
    __shared__ float As[TS_K][TS_M];
    __shared__ float Ws[TS_K][TS_N];
    __shared__ float red[256];

    const int bm = blockIdx.y * TS_M;
    const int bn = blockIdx.x * TS_N;
    const int tid = threadIdx.x;
    const int tx = tid & 15;
    const int ty = tid >> 4;
    const int lr = tid >> 2;
    const int lk = (tid & 3) * 4;

    float acc[4][4] = {};
    const int arow = bm + lr;
    const int wrow = bn + lr;

    for (int k0 = 0; k0 < K; k0 += TS_K) {
        const bool fullk = (k0 + TS_K) <= K;
        if (arow < M) {
            const float* Ap = A + (size_t)arow * K + k0 + lk;
            if (fullk) {
                float4 v = *(const float4*)Ap;
                As[lk + 0][lr] = v.x; As[lk + 1][lr] = v.y;
                As[lk + 2][lr] = v.z; As[lk + 3][lr] = v.w;
            } else {
                #pragma unroll
                for (int i = 0; i < 4; i++) {
                    int kk = k0 + lk + i;
                    As[lk + i][lr] = (kk < K) ? A[(size_t)arow * K + kk] : 0.0f;
                }
            }
        } else {
            #pragma unroll
            for (int i = 0; i < 4; i++) As[lk + i][lr] = 0.0f;
        }
        if (wrow < N) {
            const float* Wp = P + (size_t)wrow * K + k0 + lk;
            if (fullk) {
                float4 v = *(const float4*)Wp;
                Ws[lk + 0][lr] = v.x; Ws[lk + 1][lr] = v.y;
                Ws[lk + 2][lr] = v.z; Ws[lk + 3][lr] = v.w;
            } else {
                #pragma unroll
                for (int i = 0; i < 4; i++) {
                    int kk = k0 + lk + i;
                    Ws[lk + i][lr] = (kk < K) ? P[(size_t)wrow * K + kk] : 0.0f;
                }
            }
        } else {
            #pragma unroll
            for (int i = 0; i < 4; i++) Ws[lk + i][lr] = 0.0f;
        }
        __syncthreads();

        #pragma unroll
        for (int kk = 0; kk < TS_K; kk++) {
            float a4[4], b4[4];
            *(float4*)a4 = *(const float4*)&As[kk][ty * 4];
            *(float4*)b4 = *(const float4*)&Ws[kk][tx * 4];
            #pragma unroll
            for (int i = 0; i < 4; i++)
                #pragma unroll
                for (int j = 0; j < 4; j++)
                    acc[i][j] += a4[i] * b4[j];
        }
        __syncthreads();
    }

    float psum = 0.0f;
    #pragma unroll
    for (int i = 0; i < 4; i++) {
        int r = bm + ty * 4 + i;
        if (r >= M) continue;
        int objc = triples[r * 3 + 2];
        #pragma unroll
        for (int j = 0; j < 4; j++) {
            int c = bn + tx * 4 + j;
            if (c >= N) continue;
            float x = acc[i][j];
            float e = expf(-fabsf(x));              // exp(-|x|)
            float sig = (x >= 0.0f) ? 1.0f / (1.0f + e) : e / (1.0f + e);
            float sp = log1pf(e);                   // log(1+exp(-|x|))
            // logsig(x) = min(x,0) - sp ; logsig(-x) = min(-x,0) - sp
            float term = (c == objc) ? (fminf(x, 0.0f) - sp)
                                     : (fminf(-x, 0.0f) - sp);
            psum += term;
            outScore[(size_t)r * N + c] = sig;
        }
    }
    red[tid] = psum;
    __syncthreads();
    for (int s = 128; s > 0; s >>= 1) {
        if (tid < s) red[tid] += red[tid + s];
        __syncthreads();
    }
    if (tid == 0) atomicAdd(accPath, (double)red[0]);
}

__global__ __launch_bounds__(256) void masked_softmax_kernel(
    const float* __restrict__ base, const float* __restrict__ part,
    int t, float* __restrict__ aout)
{
    __shared__ float sv[RR];
    __shared__ float red[256];
    const int b = blockIdx.x;
    const int tid = threadIdx.x;
    const float* brow = base + (size_t)b * RR;
    const float* prow = part + (size_t)b * (TT * RR) + t * RR;

    float lmax = -3.0e38f;
    for (int r = tid; r < RR; r += 256) {
        float v = prow[r] * brow[r];
        if (v == 0.0f) v = -1000000000.0f;
        sv[r] = v;
        lmax = fmaxf(lmax, v);
    }
    red[tid] = lmax;
    __syncthreads();
    for (int s = 128; s > 0; s >>= 1) {
        if (tid < s) red[tid] = fmaxf(red[tid], red[tid + s]);
        __syncthreads();
    }
    float gmax = red[0];
    __syncthreads();

    float lsum = 0.0f;
    for (int r = tid; r < RR; r += 256) {
        float e = expf(sv[r] - gmax);
        sv[r] = e;
        lsum += e;
    }
    red[tid] = lsum;
    __syncthreads();
    for (int s = 128; s > 0; s >>= 1) {
        if (tid < s) red[tid] += red[tid + s];
        __syncthreads();
    }
    float inv = 1.0f / red[0];
    for (int r = tid; r < RR; r += 256)
        aout[(size_t)b * RR + r] = sv[r] * inv;
}

__global__ __launch_bounds__(256) void gru_combine_kernel(
    const float* __restrict__ gi, const float* __restrict__ gh,
    const float* __restrict__ hprev, float* __restrict__ hnew, int total)
{
    int i = blockIdx.x * 256 + threadIdx.x;
    if (i >= total) return;
    int b = i / EE, j = i - b * EE;
    size_t o = (size_t)b * 3 * EE;
    float ir = gi[o + j], iz = gi[o + EE + j], inn = gi[o + 2 * EE + j];
    float hr = gh[o + j], hz = gh[o + EE + j], hn = gh[o + 2 * EE + j];
    float r = 1.0f / (1.0f + expf(-(ir + hr)));
    float z = 1.0f / (1.0f + expf(-(iz + hz)));
    float n = tanhf(inn + r * hn);
    hnew[i] = (1.0f - z) * n + z * hprev[i];
}

__global__ __launch_bounds__(256) void gather_rows_kernel(
    const float* __restrict__ src, const int* __restrict__ idx,
    int idxStride, int idxOff, float* __restrict__ dst, int rows, int cols)
{
    int i = blockIdx.x * 256 + threadIdx.x;
    if (i >= rows * cols) return;
    int r = i / cols, c = i - r * cols;
    dst[i] = src[(size_t)idx[r * idxStride + idxOff] * cols + c];
}

__global__ __launch_bounds__(256) void transpose_kernel(
    const float* __restrict__ src, float* __restrict__ dst, int R, int C)
{
    int i = blockIdx.x * 256 + threadIdx.x;
    if (i >= R * C) return;
    int r = i / C, c = i - r * C;
    dst[(size_t)c * R + r] = src[i];
}

__global__ __launch_bounds__(256) void sqdiff_reduce_kernel(
    const float* __restrict__ a, const float* __restrict__ b, int n,
    double* __restrict__ acc)
{
    __shared__ float red[256];
    int tid = threadIdx.x;
    float s = 0.0f;
    for (int i = blockIdx.x * 256 + tid; i < n; i += gridDim.x * 256) {
        float d = a[i] - b[i];
        s += d * d;
    }
    red[tid] = s;
    __syncthreads();
    for (int st = 128; st > 0; st >>= 1) {
        if (tid < st) red[tid] += red[tid + st];
        __syncthreads();
    }
    if (tid == 0) atomicAdd(acc, (double)red[0]);
}

__global__ void final_kernel(const double* __restrict__ acc, float* __restrict__ out)
{
    if (threadIdx.x == 0) {
        out[0] = (float)(acc[0] / ((double)BB * EE));
        out[1] = (float)(-acc[1] / ((double)BB * NN));
    }
}

extern "C" void kernel_launch(void* const* d_in, const int* in_sizes, int n_in,
                              void* d_out, int out_size, void* d_ws, size_t ws_size,
                              hipStream_t stream) {
    const float* pre_emb = (const float*)d_in[0];
    const float* r_emb   = (const float*)d_in[1];
    const float* part    = (const float*)d_in[2];
    const int*   triples = (const int*)d_in[3];
    // d_in[4]=cur_ts, d_in[5]=num_rel (constants TT/RR)
    const float* W1  = (const float*)d_in[6];
    const float* b1  = (const float*)d_in[7];
    const float* W2  = (const float*)d_in[8];
    const float* b2  = (const float*)d_in[9];
    const float* Wa  = (const float*)d_in[10];
    const float* ba  = (const float*)d_in[11];
    const float* Wh1 = (const float*)d_in[12];
    const float* bh1 = (const float*)d_in[13];
    const float* Wh2 = (const float*)d_in[14];
    const float* bh2 = (const float*)d_in[15];
    const float* Wal = (const float*)d_in[16];
    const float* bal = (const float*)d_in[17];
    const float* wih = (const float*)d_in[18];
    const float* whh = (const float*)d_in[19];
    const float* bih = (const float*)d_in[20];
    const float* bhh = (const float*)d_in[21];

    float* out = (float*)d_out;
    double* acc = (double*)d_ws;     // 2 doubles: [match_sum, path_sum]
    float* wsf = (float*)d_ws;
    size_t off = 4;                  // skip 16 bytes for acc
    auto alloc = [&](size_t n) { float* p = wsf + off; off += n; return p; };

    float* h1    = alloc((size_t)RR * 400);
    float* map   = alloc((size_t)RR * EE);
    float* mapT  = alloc((size_t)EE * RR);
    float* qrel  = alloc((size_t)BB * EE);
    float* qa    = alloc((size_t)BB * EE);
    float* basep = alloc((size_t)BB * RR);
    float* aw    = alloc((size_t)BB * RR);
    float* x     = alloc((size_t)BB * EE);
    float* h0    = alloc((size_t)BB * EE);
    float* h1b   = alloc((size_t)BB * EE);
    float* gi    = alloc((size_t)BB * 3 * EE);
    float* gh    = alloc((size_t)BB * 3 * EE);
    float* ph1   = alloc((size_t)BB * EE);
    float* pred  = alloc((size_t)BB * EE);
    float* ghid2 = alloc((size_t)BB * EE);
    float* s1h   = alloc((size_t)BB * EE);
    float* P     = alloc((size_t)NN * EE);

    hipMemsetAsync(acc, 0, 2 * sizeof(double), stream);
    hipMemsetAsync(h0, 0, (size_t)BB * EE * sizeof(float), stream);

    dim3 blk(256);
    auto lgrid = [](int M, int N) { return dim3((N + TS_N - 1) / TS_N, (M + TS_M - 1) / TS_M); };

    // mapped_rel = lin(lin(r_emb, W1, b1), W2, b2)
    linear_kernel<0><<<lgrid(RR, 400), blk, 0, stream>>>(r_emb, nullptr, 0, 0, W1, b1, h1, RR, 400, EE, nullptr, 0.f);
    linear_kernel<0><<<lgrid(RR, EE), blk, 0, stream>>>(h1, nullptr, 0, 0, W2, b2, map, RR, EE, 400, nullptr, 0.f);
    transpose_kernel<<<((RR * EE) + 255) / 256, blk, 0, stream>>>(map, mapT, RR, EE);
    // q_rel gather
    gather_rows_kernel<<<((BB * EE) + 255) / 256, blk, 0, stream>>>(map, triples, 3, 1, qrel, BB, EE);
    // base = (q_rel @ Wa.T + ba) @ mapped_rel.T
    linear_kernel<0><<<lgrid(BB, EE), blk, 0, stream>>>(qrel, nullptr, 0, 0, Wa, ba, qa, BB, EE, EE, nullptr, 0.f);
    linear_kernel<0><<<lgrid(BB, RR), blk, 0, stream>>>(qa, nullptr, 0, 0, map, nullptr, basep, BB, RR, EE, nullptr, 0.f);

    // scan
    float* hc = h0;
    float* hn = h1b;
    for (int t = 0; t < TT; t++) {
        masked_softmax_kernel<<<BB, blk, 0, stream>>>(basep, part, t, aw);
        linear_kernel<0><<<lgrid(BB, EE), blk, 0, stream>>>(aw, nullptr, 0, 0, mapT, nullptr, x, BB, EE, RR, nullptr, 0.f);
        linear_kernel<0><<<lgrid(BB, 3 * EE), blk, 0, stream>>>(x, nullptr, 0, 0, wih, bih, gi, BB, 3 * EE, EE, nullptr, 0.f);
        linear_kernel<0><<<lgrid(BB, 3 * EE), blk, 0, stream>>>(hc, nullptr, 0, 0, whh, bhh, gh, BB, 3 * EE, EE, nullptr, 0.f);
        gru_combine_kernel<<<((BB * EE) + 255) / 256, blk, 0, stream>>>(gi, gh, hc, hn, BB * EE);
        float* tmp = hc; hc = hn; hn = tmp;
    }

    // predicted_hist = 0.1*lin(lin(q_rel,Wh1,bh1),Wh2,bh2) + q_rel
    linear_kernel<0><<<lgrid(BB, EE), blk, 0, stream>>>(qrel, nullptr, 0, 0, Wh1, bh1, ph1, BB, EE, EE, nullptr, 0.f);
    linear_kernel<1><<<lgrid(BB, EE), blk, 0, stream>>>(ph1, nullptr, 0, 0, Wh2, bh2, pred, BB, EE, EE, qrel, 0.1f);
    // match_loss partial
    sqdiff_reduce_kernel<<<128, blk, 0, stream>>>(pred, hc, BB * EE, acc + 0);
    // gru_hidden2 = gru_cell(q_rel, predicted_hist)
    linear_kernel<0><<<lgrid(BB, 3 * EE), blk, 0, stream>>>(qrel, nullptr, 0, 0, wih, bih, gi, BB, 3 * EE, EE, nullptr, 0.f);
    linear_kernel<0><<<lgrid(BB, 3 * EE), blk, 0, stream>>>(pred, nullptr, 0, 0, whh, bhh, gh, BB, 3 * EE, EE, nullptr, 0.f);
    gru_combine_kernel<<<((BB * EE) + 255) / 256, blk, 0, stream>>>(gi, gh, pred, ghid2, BB * EE);
    // s1h = (pre_emb[sub] @ Wal.T + bal) * gru_hidden2
    linear_kernel<2><<<lgrid(BB, EE), blk, 0, stream>>>(pre_emb, triples, 3, 0, Wal, bal, s1h, BB, EE, EE, ghid2, 0.f);
    // P = pre_emb @ Wal.T + bal
    linear_kernel<0><<<lgrid(NN, EE), blk, 0, stream>>>(pre_emb, nullptr, 0, 0, Wal, bal, P, NN, EE, EE, nullptr, 0.f);
    // score + path loss
    score_kernel<<<dim3(NN / TS_N, BB / TS_M), blk, 0, stream>>>(s1h, P, triples, out + 2, acc + 1, BB, NN, EE);
    // finalize losses
    final_kernel<<<1, 64, 0, stream>>>(acc, out);
}

// Round 2
// 753.940 us; speedup vs baseline: 1.7810x; 1.7810x over previous
//
#include <hip/hip_runtime.h>
#include <hip/hip_bf16.h>
#include <math.h>

// Problem constants
#define EE 200
#define RR 480
#define TT 8
#define NN 40000
#define BB 1024
#define KP 224   // K=200 padded to multiple of 32 for MFMA

#define TS_M 64
#define TS_N 64
#define TS_K 16

typedef __attribute__((ext_vector_type(8))) short short8v;   // 8 bf16 (4 VGPRs)
typedef __attribute__((ext_vector_type(4))) float f32x4;

__device__ inline unsigned short f2bf(float x) {  // RNE fp32->bf16
    unsigned int u = __float_as_uint(x);
    unsigned int r = ((u >> 16) & 1u) + 0x7fffu;
    return (unsigned short)((u + r) >> 16);
}

// Generic tiled linear: C[M,N] = A[M,K] @ W[N,K]^T (+ bias)
// MODE 0: C = acc + bias
// MODE 1: C = alpha*(acc + bias) + extra[r*N+c]
// MODE 2: C = (acc + bias) * extra[r*N+c]
// OUTBF16: write bf16 to (unsigned short*)Cvoid with row stride obfStride,
//          zero-filling columns [N, obfStride).
template <int MODE, int OUTBF16>
__global__ __launch_bounds__(256) void linear_kernel(
    const float* __restrict__ A, const int* __restrict__ gidx, int gstride, int goff,
    const float* __restrict__ W, const float* __restrict__ bias,
    void* __restrict__ Cvoid, int M, int N, int K,
    const float* __restrict__ extra, float alpha, int obfStride)
{
    __shared__ float As[TS_K][TS_M];
    __shared__ float Ws[TS_K][TS_N];

    const int bm = blockIdx.y * TS_M;
    const int bn = blockIdx.x * TS_N;
    const int tid = threadIdx.x;
    const int tx = tid & 15;       // 0..15
    const int ty = tid >> 4;       // 0..15
    const int lr = tid >> 2;       // 0..63 (tile row for loads)
    const int lk = (tid & 3) * 4;  // 0,4,8,12

    float acc[4][4] = {};

    const int arow = bm + lr;
    int srow = -1;
    if (arow < M) srow = gidx ? gidx[arow * gstride + goff] : arow;
    const int wrow = bn + lr;

    for (int k0 = 0; k0 < K; k0 += TS_K) {
        const bool fullk = (k0 + TS_K) <= K;
        if (srow >= 0) {
            const float* Ap = A + (size_t)srow * K + k0 + lk;
            if (fullk) {
                float4 v = *(const float4*)Ap;
                As[lk + 0][lr] = v.x; As[lk + 1][lr] = v.y;
                As[lk + 2][lr] = v.z; As[lk + 3][lr] = v.w;
            } else {
                #pragma unroll
                for (int i = 0; i < 4; i++) {
                    int kk = k0 + lk + i;
                    As[lk + i][lr] = (kk < K) ? A[(size_t)srow * K + kk] : 0.0f;
                }
            }
        } else {
            #pragma unroll
            for (int i = 0; i < 4; i++) As[lk + i][lr] = 0.0f;
        }
        if (wrow < N) {
            const float* Wp = W + (size_t)wrow * K + k0 + lk;
            if (fullk) {
                float4 v = *(const float4*)Wp;
                Ws[lk + 0][lr] = v.x; Ws[lk + 1][lr] = v.y;
                Ws[lk + 2][lr] = v.z; Ws[lk + 3][lr] = v.w;
            } else {
                #pragma unroll
                for (int i = 0; i < 4; i++) {
                    int kk = k0 + lk + i;
                    Ws[lk + i][lr] = (kk < K) ? W[(size_t)wrow * K + kk] : 0.0f;
                }
            }
        } else {
            #pragma unroll
            for (int i = 0; i < 4; i++) Ws[lk + i][lr] = 0.0f;
        }
        __syncthreads();

        #pragma unroll
        for (int kk = 0; kk < TS_K; kk++) {
            float a4[4], b4[4];
            *(float4*)a4 = *(const float4*)&As[kk][ty * 4];
            *(float4*)b4 = *(const float4*)&Ws[kk][tx * 4];
            #pragma unroll
            for (int i = 0; i < 4; i++)
                #pragma unroll
                for (int j = 0; j < 4; j++)
                    acc[i][j] += a4[i] * b4[j];
        }
        __syncthreads();
    }

    #pragma unroll
    for (int i = 0; i < 4; i++) {
        int r = bm + ty * 4 + i;
        if (r >= M) continue;
        #pragma unroll
        for (int j = 0; j < 4; j++) {
            int c = bn + tx * 4 + j;
            if (OUTBF16) {
                if (c >= obfStride) continue;
                float v = 0.0f;
                if (c < N) {
                    v = acc[i][j];
                    if (bias) v += bias[c];
                    if (MODE == 2) v *= extra[(size_t)r * N + c];
                }
                ((unsigned short*)Cvoid)[(size_t)r * obfStride + c] = f2bf(v);
            } else {
                if (c >= N) continue;
                float v = acc[i][j];
                if (bias) v += bias[c];
                if (MODE == 1) v = alpha * v + extra[(size_t)r * N + c];
                else if (MODE == 2) v = v * extra[(size_t)r * N + c];
                ((float*)Cvoid)[(size_t)r * N + c] = v;
            }
        }
    }
}

// score = sigmoid(s1h @ P^T) via bf16 MFMA, fused path-loss partial sums.
// A,P row-major bf16 with row stride KP (zero-padded cols 200..223).
__global__ __launch_bounds__(256) void score_mfma_kernel(
    const unsigned short* __restrict__ Abf,   // [BB][KP]
    const unsigned short* __restrict__ Pbf,   // [NN][KP]
    const int* __restrict__ triples,
    float* __restrict__ outScore,             // [BB][NN]
    double* __restrict__ accPath)
{
    __shared__ float red[256];
    const int tid  = threadIdx.x;
    const int wave = tid >> 6;        // 0..3
    const int lane = tid & 63;
    const int bm = blockIdx.y * 64 + wave * 16;
    const int bn = blockIdx.x * 64;
    const int r16   = lane & 15;
    const int khalf = lane >> 4;      // 0..3
    const int kbase = khalf * 8;

    const unsigned short* Ap = Abf + (size_t)(bm + r16) * KP + kbase;
    const unsigned short* Pp = Pbf + (size_t)(bn + r16) * KP + kbase;

    f32x4 acc0 = {0,0,0,0}, acc1 = {0,0,0,0}, acc2 = {0,0,0,0}, acc3 = {0,0,0,0};

    #pragma unroll
    for (int k0 = 0; k0 < KP; k0 += 32) {
        short8v a  = *(const short8v*)(Ap + k0);
        short8v b0 = *(const short8v*)(Pp + k0);
        short8v b1 = *(const short8v*)(Pp + (size_t)16 * KP + k0);
        short8v b2 = *(const short8v*)(Pp + (size_t)32 * KP + k0);
        short8v b3 = *(const short8v*)(Pp + (size_t)48 * KP + k0);
        acc0 = __builtin_amdgcn_mfma_f32_16x16x32_bf16(a, b0, acc0, 0, 0, 0);
        acc1 = __builtin_amdgcn_mfma_f32_16x16x32_bf16(a, b1, acc1, 0, 0, 0);
        acc2 = __builtin_amdgcn_mfma_f32_16x16x32_bf16(a, b2, acc2, 0, 0, 0);
        acc3 = __builtin_amdgcn_mfma_f32_16x16x32_bf16(a, b3, acc3, 0, 0, 0);
    }

    float psum = 0.0f;
    #pragma unroll
    for (int r = 0; r < 4; r++) {
        const int grow = bm + khalf * 4 + r;
        const int objc = triples[grow * 3 + 2];
        float xv[4] = { acc0[r], acc1[r], acc2[r], acc3[r] };
        #pragma unroll
        for (int nf = 0; nf < 4; nf++) {
            const int col = bn + nf * 16 + r16;
            float x = xv[nf];
            float e = __expf(-fabsf(x));                 // exp(-|x|)
            float sig = (x >= 0.0f) ? 1.0f / (1.0f + e) : e / (1.0f + e);
            float sp = log1pf(e);                        // log(1+exp(-|x|))
            float term = (col == objc) ? (fminf(x, 0.0f) - sp)
                                       : (fminf(-x, 0.0f) - sp);
            psum += term;
            outScore[(size_t)grow * NN + col] = sig;
        }
    }
    red[tid] = psum;
    __syncthreads();
    for (int s = 128; s > 0; s >>= 1) {
        if (tid < s) red[tid] += red[tid + s];
        __syncthreads();
    }
    if (tid == 0) atomicAdd(accPath, (double)red[0]);
}

// All-t masked softmax: block = (t*BB + b), writes aw_all[(t*BB+b)][RR]
__global__ __launch_bounds__(256) void masked_softmax_all_kernel(
    const float* __restrict__ base, const float* __restrict__ part,
    float* __restrict__ aout)
{
    __shared__ float sv[RR];
    __shared__ float red[256];
    const int blk = blockIdx.x;
    const int b = blk & (BB - 1);
    const int t = blk >> 10;
    const int tid = threadIdx.x;
    const float* brow = base + (size_t)b * RR;
    const float* prow = part + (size_t)b * (TT * RR) + t * RR;

    float lmax = -3.0e38f;
    for (int r = tid; r < RR; r += 256) {
        float v = prow[r] * brow[r];
        if (v == 0.0f) v = -1000000000.0f;
        sv[r] = v;
        lmax = fmaxf(lmax, v);
    }
    red[tid] = lmax;
    __syncthreads();
    for (int s = 128; s > 0; s >>= 1) {
        if (tid < s) red[tid] = fmaxf(red[tid], red[tid + s]);
        __syncthreads();
    }
    float gmax = red[0];
    __syncthreads();

    float lsum = 0.0f;
    for (int r = tid; r < RR; r += 256) {
        float e = expf(sv[r] - gmax);
        sv[r] = e;
        lsum += e;
    }
    red[tid] = lsum;
    __syncthreads();
    for (int s = 128; s > 0; s >>= 1) {
        if (tid < s) red[tid] += red[tid + s];
        __syncthreads();
    }
    float inv = 1.0f / red[0];
    for (int r = tid; r < RR; r += 256)
        aout[(size_t)blk * RR + r] = sv[r] * inv;
}

__global__ __launch_bounds__(256) void gru_combine_kernel(
    const float* __restrict__ gi, const float* __restrict__ gh,
    const float* __restrict__ hprev, float* __restrict__ hnew, int total)
{
    int i = blockIdx.x * 256 + threadIdx.x;
    if (i >= total) return;
    int b = i / EE, j = i - b * EE;
    size_t o = (size_t)b * 3 * EE;
    float ir = gi[o + j], iz = gi[o + EE + j], inn = gi[o + 2 * EE + j];
    float hr = gh[o + j], hz = gh[o + EE + j], hn = gh[o + 2 * EE + j];
    float r = 1.0f / (1.0f + expf(-(ir + hr)));
    float z = 1.0f / (1.0f + expf(-(iz + hz)));
    float n = tanhf(inn + r * hn);
    hnew[i] = (1.0f - z) * n + z * hprev[i];
}

__global__ __launch_bounds__(256) void gather_rows_kernel(
    const float* __restrict__ src, const int* __restrict__ idx,
    int idxStride, int idxOff, float* __restrict__ dst, int rows, int cols)
{
    int i = blockIdx.x * 256 + threadIdx.x;
    if (i >= rows * cols) return;
    int r = i / cols, c = i - r * cols;
    dst[i] = src[(size_t)idx[r * idxStride + idxOff] * cols + c];
}

__global__ __launch_bounds__(256) void sqdiff_reduce_kernel(
    const float* __restrict__ a, const float* __restrict__ b, int n,
    double* __restrict__ acc)
{
    __shared__ float red[256];
    int tid = threadIdx.x;
    float s = 0.0f;
    for (int i = blockIdx.x * 256 + tid; i < n; i += gridDim.x * 256) {
        float d = a[i] - b[i];
        s += d * d;
    }
    red[tid] = s;
    __syncthreads();
    for (int st = 128; st > 0; st >>= 1) {
        if (tid < st) red[tid] += red[tid + st];
        __syncthreads();
    }
    if (tid == 0) atomicAdd(acc, (double)red[0]);
}

__global__ void final_kernel(const double* __restrict__ acc, float* __restrict__ out)
{
    if (threadIdx.x == 0) {
        out[0] = (float)(acc[0] / ((double)BB * EE));
        out[1] = (float)(-acc[1] / ((double)BB * NN));
    }
}

extern "C" void kernel_launch(void* const* d_in, const int* in_sizes, int n_in,
                              void* d_out, int out_size, void* d_ws, size_t ws_size,
                              hipStream_t stream) {
    const float* pre_emb = (const float*)d_in[0];
    const float* r_emb   = (const float*)d_in[1];
    const float* part    = (const float*)d_in[2];
    const int*   triples = (const int*)d_in[3];
    const float* W1  = (const float*)d_in[6];
    const float* b1  = (const float*)d_in[7];
    const float* W2  = (const float*)d_in[8];
    const float* b2  = (const float*)d_in[9];
    const float* Wa  = (const float*)d_in[10];
    const float* ba  = (const float*)d_in[11];
    const float* Wh1 = (const float*)d_in[12];
    const float* bh1 = (const float*)d_in[13];
    const float* Wh2 = (const float*)d_in[14];
    const float* bh2 = (const float*)d_in[15];
    const float* Wal = (const float*)d_in[16];
    const float* bal = (const float*)d_in[17];
    const float* wih = (const float*)d_in[18];
    const float* whh = (const float*)d_in[19];
    const float* bih = (const float*)d_in[20];
    const float* bhh = (const float*)d_in[21];

    float* out = (float*)d_out;
    double* acc = (double*)d_ws;     // 2 doubles: [match_sum, path_sum]
    float* wsf = (float*)d_ws;
    size_t off = 4;                  // skip 16 bytes for acc
    auto alloc = [&](size_t n) { float* p = wsf + off; off += (n + 3) & ~(size_t)3; return p; };

    float* h1     = alloc((size_t)RR * 400);
    float* map    = alloc((size_t)RR * EE);
    float* qrel   = alloc((size_t)BB * EE);
    float* qa     = alloc((size_t)BB * EE);
    float* basep  = alloc((size_t)BB * RR);
    float* aw_all = alloc((size_t)TT * BB * RR);
    float* Wgi    = alloc((size_t)600 * RR);
    float* gi_all = alloc((size_t)TT * BB * 3 * EE);
    float* gh     = alloc((size_t)BB * 3 * EE);
    float* h0     = alloc((size_t)BB * EE);
    float* h1b    = alloc((size_t)BB * EE);
    float* ph1    = alloc((size_t)BB * EE);
    float* pred   = alloc((size_t)BB * EE);
    float* ghid2  = alloc((size_t)BB * EE);
    unsigned short* s1h_bf = (unsigned short*)alloc((size_t)BB * KP / 2);
    unsigned short* P_bf   = (unsigned short*)alloc((size_t)NN * KP / 2);

    hipMemsetAsync(acc, 0, 2 * sizeof(double), stream);
    hipMemsetAsync(h0, 0, (size_t)BB * EE * sizeof(float), stream);

    dim3 blk(256);
    auto lgrid = [](int M, int N) { return dim3((N + TS_N - 1) / TS_N, (M + TS_M - 1) / TS_M); };

    // mapped_rel = lin(lin(r_emb, W1, b1), W2, b2)
    linear_kernel<0,0><<<lgrid(RR, 400), blk, 0, stream>>>(r_emb, nullptr, 0, 0, W1, b1, h1, RR, 400, EE, nullptr, 0.f, 0);
    linear_kernel<0,0><<<lgrid(RR, EE), blk, 0, stream>>>(h1, nullptr, 0, 0, W2, b2, map, RR, EE, 400, nullptr, 0.f, 0);
    // q_rel gather
    gather_rows_kernel<<<((BB * EE) + 255) / 256, blk, 0, stream>>>(map, triples, 3, 1, qrel, BB, EE);
    // base = (q_rel @ Wa.T + ba) @ mapped_rel.T
    linear_kernel<0,0><<<lgrid(BB, EE), blk, 0, stream>>>(qrel, nullptr, 0, 0, Wa, ba, qa, BB, EE, EE, nullptr, 0.f, 0);
    linear_kernel<0,0><<<lgrid(BB, RR), blk, 0, stream>>>(qa, nullptr, 0, 0, map, nullptr, basep, BB, RR, EE, nullptr, 0.f, 0);

    // All softmaxes at once (attn depends only on base & partial, not h)
    masked_softmax_all_kernel<<<TT * BB, blk, 0, stream>>>(basep, part, aw_all);
    // Wgi = wih @ map.T  (600x480), then gi_all = aw_all @ Wgi.T + bih  (8192x600)
    linear_kernel<0,0><<<lgrid(600, RR), blk, 0, stream>>>(wih, nullptr, 0, 0, map, nullptr, Wgi, 600, RR, EE, nullptr, 0.f, 0);
    linear_kernel<0,0><<<lgrid(TT * BB, 3 * EE), blk, 0, stream>>>(aw_all, nullptr, 0, 0, Wgi, bih, gi_all, TT * BB, 3 * EE, RR, nullptr, 0.f, 0);

    // scan: only gh + combine are sequential
    float* hc = h0;
    float* hn = h1b;
    for (int t = 0; t < TT; t++) {
        linear_kernel<0,0><<<lgrid(BB, 3 * EE), blk, 0, stream>>>(hc, nullptr, 0, 0, whh, bhh, gh, BB, 3 * EE, EE, nullptr, 0.f, 0);
        gru_combine_kernel<<<((BB * EE) + 255) / 256, blk, 0, stream>>>(gi_all + (size_t)t * BB * 3 * EE, gh, hc, hn, BB * EE);
        float* tmp = hc; hc = hn; hn = tmp;
    }

    // predicted_hist = 0.1*lin(lin(q_rel,Wh1,bh1),Wh2,bh2) + q_rel
    linear_kernel<0,0><<<lgrid(BB, EE), blk, 0, stream>>>(qrel, nullptr, 0, 0, Wh1, bh1, ph1, BB, EE, EE, nullptr, 0.f, 0);
    linear_kernel<1,0><<<lgrid(BB, EE), blk, 0, stream>>>(ph1, nullptr, 0, 0, Wh2, bh2, pred, BB, EE, EE, qrel, 0.1f, 0);
    // match_loss partial
    sqdiff_reduce_kernel<<<128, blk, 0, stream>>>(pred, hc, BB * EE, acc + 0);
    // gru_hidden2 = gru_cell(q_rel, predicted_hist) — reuse gi_all/gh buffers
    linear_kernel<0,0><<<lgrid(BB, 3 * EE), blk, 0, stream>>>(qrel, nullptr, 0, 0, wih, bih, gi_all, BB, 3 * EE, EE, nullptr, 0.f, 0);
    linear_kernel<0,0><<<lgrid(BB, 3 * EE), blk, 0, stream>>>(pred, nullptr, 0, 0, whh, bhh, gh, BB, 3 * EE, EE, nullptr, 0.f, 0);
    gru_combine_kernel<<<((BB * EE) + 255) / 256, blk, 0, stream>>>(gi_all, gh, pred, ghid2, BB * EE);
    // s1h = (pre_emb[sub] @ Wal.T + bal) * gru_hidden2  -> bf16 padded
    linear_kernel<2,1><<<lgrid(BB, KP), blk, 0, stream>>>(pre_emb, triples, 3, 0, Wal, bal, s1h_bf, BB, EE, EE, ghid2, 0.f, KP);
    // P = pre_emb @ Wal.T + bal  -> bf16 padded
    linear_kernel<0,1><<<lgrid(NN, KP), blk, 0, stream>>>(pre_emb, nullptr, 0, 0, Wal, bal, P_bf, NN, EE, EE, nullptr, 0.f, KP);
    // score + path loss (bf16 MFMA)
    score_mfma_kernel<<<dim3(NN / 64, BB / 64), blk, 0, stream>>>(s1h_bf, P_bf, triples, out + 2, acc + 1);
    // finalize losses
    final_kernel<<<1, 64, 0, stream>>>(acc, out);
}

// Round 3
// 554.587 us; speedup vs baseline: 2.4212x; 1.3595x over previous
//
#include <hip/hip_runtime.h>
#include <hip/hip_bf16.h>
#include <math.h>

// Problem constants
#define EE 200
#define RR 480
#define TT 8
#define NN 40000
#define BB 1024
#define KP 224        // K=200 padded to multiple of 32 for MFMA
#define NPAD 640      // padded B-row count for N=600 MFMA GEMMs
#define LDS_STRIDE 232  // shorts per LDS row (224 + 8 pad -> 2-way bank conflict = free)

#define TS_M 64
#define TS_N 64
#define TS_K 16

typedef __attribute__((ext_vector_type(8))) short short8v;   // 8 bf16 (4 VGPRs)
typedef __attribute__((ext_vector_type(4))) float f32x4;

__device__ inline unsigned short f2bf(float x) {  // RNE fp32->bf16
    unsigned int u = __float_as_uint(x);
    unsigned int r = ((u >> 16) & 1u) + 0x7fffu;
    return (unsigned short)((u + r) >> 16);
}
__device__ inline float bf2f(unsigned short h) {
    return __uint_as_float(((unsigned int)h) << 16);
}

// ---------------------------------------------------------------------------
// Generic tiled fp32 linear: C[M,N] = A[M,K] @ W[N,K]^T (+ bias)
// MODE 0: C = acc + bias
// MODE 1: C = alpha*(acc + bias) + extra[r*N+c]
// MODE 2: C = (acc + bias) * extra[r*N+c]
// OUTBF16 0: fp32 out. 1: bf16 out (stride obfStride, zero-pad cols >= N).
// OUTBF16 2: bf16 hi/lo split out (Cvoid = hi, Cvoid2 = lo).
template <int MODE, int OUTBF16>
__global__ __launch_bounds__(256) void linear_kernel(
    const float* __restrict__ A, const int* __restrict__ gidx, int gstride, int goff,
    const float* __restrict__ W, const float* __restrict__ bias,
    void* __restrict__ Cvoid, void* __restrict__ Cvoid2, int M, int N, int K,
    const float* __restrict__ extra, float alpha, int obfStride)
{
    __shared__ float As[TS_K][TS_M];
    __shared__ float Ws[TS_K][TS_N];

    const int bm = blockIdx.y * TS_M;
    const int bn = blockIdx.x * TS_N;
    const int tid = threadIdx.x;
    const int tx = tid & 15;
    const int ty = tid >> 4;
    const int lr = tid >> 2;
    const int lk = (tid & 3) * 4;

    float acc[4][4] = {};

    const int arow = bm + lr;
    int srow = -1;
    if (arow < M) srow = gidx ? gidx[arow * gstride + goff] : arow;
    const int wrow = bn + lr;

    for (int k0 = 0; k0 < K; k0 += TS_K) {
        const bool fullk = (k0 + TS_K) <= K;
        if (srow >= 0) {
            const float* Ap = A + (size_t)srow * K + k0 + lk;
            if (fullk) {
                float4 v = *(const float4*)Ap;
                As[lk + 0][lr] = v.x; As[lk + 1][lr] = v.y;
                As[lk + 2][lr] = v.z; As[lk + 3][lr] = v.w;
            } else {
                #pragma unroll
                for (int i = 0; i < 4; i++) {
                    int kk = k0 + lk + i;
                    As[lk + i][lr] = (kk < K) ? A[(size_t)srow * K + kk] : 0.0f;
                }
            }
        } else {
            #pragma unroll
            for (int i = 0; i < 4; i++) As[lk + i][lr] = 0.0f;
        }
        if (wrow < N) {
            const float* Wp = W + (size_t)wrow * K + k0 + lk;
            if (fullk) {
                float4 v = *(const float4*)Wp;
                Ws[lk + 0][lr] = v.x; Ws[lk + 1][lr] = v.y;
                Ws[lk + 2][lr] = v.z; Ws[lk + 3][lr] = v.w;
            } else {
                #pragma unroll
                for (int i = 0; i < 4; i++) {
                    int kk = k0 + lk + i;
                    Ws[lk + i][lr] = (kk < K) ? W[(size_t)wrow * K + kk] : 0.0f;
                }
            }
        } else {
            #pragma unroll
            for (int i = 0; i < 4; i++) Ws[lk + i][lr] = 0.0f;
        }
        __syncthreads();

        #pragma unroll
        for (int kk = 0; kk < TS_K; kk++) {
            float a4[4], b4[4];
            *(float4*)a4 = *(const float4*)&As[kk][ty * 4];
            *(float4*)b4 = *(const float4*)&Ws[kk][tx * 4];
            #pragma unroll
            for (int i = 0; i < 4; i++)
                #pragma unroll
                for (int j = 0; j < 4; j++)
                    acc[i][j] += a4[i] * b4[j];
        }
        __syncthreads();
    }

    #pragma unroll
    for (int i = 0; i < 4; i++) {
        int r = bm + ty * 4 + i;
        if (r >= M) continue;
        #pragma unroll
        for (int j = 0; j < 4; j++) {
            int c = bn + tx * 4 + j;
            if (OUTBF16) {
                if (c >= obfStride) continue;
                float v = 0.0f;
                if (c < N) {
                    v = acc[i][j];
                    if (bias) v += bias[c];
                    if (MODE == 2) v *= extra[(size_t)r * N + c];
                }
                unsigned short h = f2bf(v);
                ((unsigned short*)Cvoid)[(size_t)r * obfStride + c] = h;
                if (OUTBF16 == 2)
                    ((unsigned short*)Cvoid2)[(size_t)r * obfStride + c] = f2bf(v - bf2f(h));
            } else {
                if (c >= N) continue;
                float v = acc[i][j];
                if (bias) v += bias[c];
                if (MODE == 1) v = alpha * v + extra[(size_t)r * N + c];
                else if (MODE == 2) v = v * extra[(size_t)r * N + c];
                ((float*)Cvoid)[(size_t)r * N + c] = v;
            }
        }
    }
}

// ---------------------------------------------------------------------------
// bf16x3 split-precision MFMA linear: C = (Ahi+Alo) @ (Bhi+Blo)^T + bias
// (drops lo*lo term; ~fp32 accuracy). A[M][Ks], B[Npad][Ks] row-major bf16.
__global__ __launch_bounds__(256) void mfma_linear3_kernel(
    const unsigned short* __restrict__ Ahi, const unsigned short* __restrict__ Alo,
    const unsigned short* __restrict__ Bhi, const unsigned short* __restrict__ Blo,
    const float* __restrict__ bias, float* __restrict__ C,
    int M, int N, int Ks)
{
    const int tid  = threadIdx.x;
    const int wave = tid >> 6;
    const int lane = tid & 63;
    const int r16   = lane & 15;
    const int khalf = lane >> 4;
    const int kbase = khalf * 8;
    const int bm = blockIdx.y * 64 + wave * 16;
    const int bn = blockIdx.x * 64;

    const unsigned short* ah = Ahi + (size_t)(bm + r16) * Ks + kbase;
    const unsigned short* al = Alo + (size_t)(bm + r16) * Ks + kbase;
    const unsigned short* bh = Bhi + (size_t)(bn + r16) * Ks + kbase;
    const unsigned short* bl = Blo + (size_t)(bn + r16) * Ks + kbase;

    f32x4 acc[4] = {{0,0,0,0},{0,0,0,0},{0,0,0,0},{0,0,0,0}};

    for (int k0 = 0; k0 < Ks; k0 += 32) {
        short8v a0 = *(const short8v*)(ah + k0);
        short8v a1 = *(const short8v*)(al + k0);
        #pragma unroll
        for (int nf = 0; nf < 4; nf++) {
            short8v b0 = *(const short8v*)(bh + (size_t)nf * 16 * Ks + k0);
            short8v b1 = *(const short8v*)(bl + (size_t)nf * 16 * Ks + k0);
            acc[nf] = __builtin_amdgcn_mfma_f32_16x16x32_bf16(a0, b1, acc[nf], 0, 0, 0);
            acc[nf] = __builtin_amdgcn_mfma_f32_16x16x32_bf16(a1, b0, acc[nf], 0, 0, 0);
            acc[nf] = __builtin_amdgcn_mfma_f32_16x16x32_bf16(a0, b0, acc[nf], 0, 0, 0);
        }
    }
    #pragma unroll
    for (int r = 0; r < 4; r++) {
        const int row = bm + khalf * 4 + r;
        #pragma unroll
        for (int nf = 0; nf < 4; nf++) {
            const int col = bn + nf * 16 + r16;
            if (col < N)
                C[(size_t)row * N + col] = acc[nf][r] + (bias ? bias[col] : 0.0f);
        }
    }
}

// ---------------------------------------------------------------------------
// score = sigmoid(u @ pre_emb^T) with bal folded into padding col 200.
// One block per 64 N-cols; pre tile converted fp32->bf16 into LDS once;
// loop over all 16 M-tiles. Fused cheap-math path loss.
__global__ __launch_bounds__(256) void score_mfma2_kernel(
    const unsigned short* __restrict__ Ubf,   // [BB][KP] (col 200 = s1h.bal, 201..223 = 0)
    const float* __restrict__ pre_emb,        // [NN][EE] fp32
    const int* __restrict__ triples,
    float* __restrict__ outScore,             // [BB][NN]
    double* __restrict__ accPath)
{
    __shared__ unsigned short Bs[64 * LDS_STRIDE];
    __shared__ int objs[BB];
    __shared__ float red[256];

    const int tid = threadIdx.x;
    const int bn = blockIdx.x * 64;

    for (int i = tid; i < BB; i += 256) objs[i] = triples[i * 3 + 2];

    // stage pre rows bn..bn+63 as bf16; col 200 = 1.0; 201..223 = 0
    for (int idx = tid; idx < 64 * 50; idx += 256) {
        int row = idx / 50;
        int c4 = (idx - row * 50) * 4;
        float4 v = *(const float4*)(pre_emb + (size_t)(bn + row) * EE + c4);
        unsigned short* d = &Bs[row * LDS_STRIDE + c4];
        d[0] = f2bf(v.x); d[1] = f2bf(v.y); d[2] = f2bf(v.z); d[3] = f2bf(v.w);
    }
    for (int idx = tid; idx < 64 * 24; idx += 256) {
        int row = idx / 24;
        int cc = idx - row * 24;
        Bs[row * LDS_STRIDE + 200 + cc] = (cc == 0) ? (unsigned short)0x3F80 : (unsigned short)0;
    }
    __syncthreads();

    const int wave  = tid >> 6;
    const int lane  = tid & 63;
    const int r16   = lane & 15;
    const int khalf = lane >> 4;
    const int kbase = khalf * 8;

    const unsigned short* bs0 = &Bs[( 0 + r16) * LDS_STRIDE + kbase];
    const unsigned short* bs1 = &Bs[(16 + r16) * LDS_STRIDE + kbase];
    const unsigned short* bs2 = &Bs[(32 + r16) * LDS_STRIDE + kbase];
    const unsigned short* bs3 = &Bs[(48 + r16) * LDS_STRIDE + kbase];

    float psum = 0.0f;

    for (int m0 = 0; m0 < BB; m0 += 64) {
        const unsigned short* Ap = Ubf + (size_t)(m0 + wave * 16 + r16) * KP + kbase;
        f32x4 acc0 = {0,0,0,0}, acc1 = {0,0,0,0}, acc2 = {0,0,0,0}, acc3 = {0,0,0,0};
        #pragma unroll
        for (int k0 = 0; k0 < KP; k0 += 32) {
            short8v a  = *(const short8v*)(Ap + k0);
            short8v b0 = *(const short8v*)(bs0 + k0);
            short8v b1 = *(const short8v*)(bs1 + k0);
            short8v b2 = *(const short8v*)(bs2 + k0);
            short8v b3 = *(const short8v*)(bs3 + k0);
            acc0 = __builtin_amdgcn_mfma_f32_16x16x32_bf16(a, b0, acc0, 0, 0, 0);
            acc1 = __builtin_amdgcn_mfma_f32_16x16x32_bf16(a, b1, acc1, 0, 0, 0);
            acc2 = __builtin_amdgcn_mfma_f32_16x16x32_bf16(a, b2, acc2, 0, 0, 0);
            acc3 = __builtin_amdgcn_mfma_f32_16x16x32_bf16(a, b3, acc3, 0, 0, 0);
        }
        #pragma unroll
        for (int r = 0; r < 4; r++) {
            const int grow = m0 + wave * 16 + khalf * 4 + r;
            const int objc = objs[grow];
            float xv[4] = { acc0[r], acc1[r], acc2[r], acc3[r] };
            #pragma unroll
            for (int nf = 0; nf < 4; nf++) {
                const int col = bn + nf * 16 + r16;
                float x  = xv[nf];
                float e  = __expf(-fabsf(x));
                float t1 = 1.0f + e;
                float rc = __builtin_amdgcn_rcpf(t1);
                float sig = (x >= 0.0f) ? rc : e * rc;
                float sp = __logf(t1);
                float s  = (col == objc) ? x : -x;
                psum += fminf(s, 0.0f) - sp;
                outScore[(size_t)grow * NN + col] = sig;
            }
        }
    }
    red[tid] = psum;
    __syncthreads();
    for (int s = 128; s > 0; s >>= 1) {
        if (tid < s) red[tid] += red[tid + s];
        __syncthreads();
    }
    if (tid == 0) atomicAdd(accPath, (double)red[0]);
}

// ---------------------------------------------------------------------------
__global__ __launch_bounds__(256) void masked_softmax_all_kernel(
    const float* __restrict__ base, const float* __restrict__ part,
    unsigned short* __restrict__ aout_hi, unsigned short* __restrict__ aout_lo)
{
    __shared__ float sv[RR];
    __shared__ float red[256];
    const int blk = blockIdx.x;
    const int b = blk & (BB - 1);
    const int t = blk >> 10;
    const int tid = threadIdx.x;
    const float* brow = base + (size_t)b * RR;
    const float* prow = part + (size_t)b * (TT * RR) + t * RR;

    float lmax = -3.0e38f;
    for (int r = tid; r < RR; r += 256) {
        float v = prow[r] * brow[r];
        if (v == 0.0f) v = -1000000000.0f;
        sv[r] = v;
        lmax = fmaxf(lmax, v);
    }
    red[tid] = lmax;
    __syncthreads();
    for (int s = 128; s > 0; s >>= 1) {
        if (tid < s) red[tid] = fmaxf(red[tid], red[tid + s]);
        __syncthreads();
    }
    float gmax = red[0];
    __syncthreads();

    float lsum = 0.0f;
    for (int r = tid; r < RR; r += 256) {
        float e = __expf(sv[r] - gmax);
        sv[r] = e;
        lsum += e;
    }
    red[tid] = lsum;
    __syncthreads();
    for (int s = 128; s > 0; s >>= 1) {
        if (tid < s) red[tid] += red[tid + s];
        __syncthreads();
    }
    float inv = 1.0f / red[0];
    for (int r = tid; r < RR; r += 256) {
        float w = sv[r] * inv;
        unsigned short h = f2bf(w);
        aout_hi[(size_t)blk * RR + r] = h;
        aout_lo[(size_t)blk * RR + r] = f2bf(w - bf2f(h));
    }
}

// SPLIT=1 also emits h as padded bf16 hi/lo for the next step's MFMA.
template <int SPLIT>
__global__ __launch_bounds__(256) void gru_combine_kernel(
    const float* __restrict__ gi, const float* __restrict__ gh,
    const float* __restrict__ hprev, float* __restrict__ hnew,
    unsigned short* __restrict__ hhi, unsigned short* __restrict__ hlo)
{
    int i = blockIdx.x * 256 + threadIdx.x;
    if (i >= BB * EE) return;
    int b = i / EE, j = i - b * EE;
    size_t o = (size_t)b * 3 * EE;
    float ir = gi[o + j], iz = gi[o + EE + j], inn = gi[o + 2 * EE + j];
    float hr = gh[o + j], hz = gh[o + EE + j], hn_ = gh[o + 2 * EE + j];
    float r = 1.0f / (1.0f + __expf(-(ir + hr)));
    float z = 1.0f / (1.0f + __expf(-(iz + hz)));
    float n = tanhf(inn + r * hn_);
    float h = (1.0f - z) * n + z * hprev[i];
    hnew[i] = h;
    if (SPLIT) {
        unsigned short hi = f2bf(h);
        hhi[(size_t)b * KP + j] = hi;
        hlo[(size_t)b * KP + j] = f2bf(h - bf2f(hi));
    }
}

__global__ __launch_bounds__(256) void gather_rows_kernel(
    const float* __restrict__ src, const int* __restrict__ idx,
    int idxStride, int idxOff, float* __restrict__ dst, int rows, int cols)
{
    int i = blockIdx.x * 256 + threadIdx.x;
    if (i >= rows * cols) return;
    int r = i / cols, c = i - r * cols;
    dst[i] = src[(size_t)idx[r * idxStride + idxOff] * cols + c];
}

// fp32[M][K] -> bf16 hi/lo [Mpad][Kp], zero pads.
__global__ __launch_bounds__(256) void convert_split_kernel(
    const float* __restrict__ src, int M, int K, int Mpad, int Kp,
    unsigned short* __restrict__ hi, unsigned short* __restrict__ lo)
{
    int i = blockIdx.x * 256 + threadIdx.x;
    if (i >= Mpad * Kp) return;
    int r = i / Kp, c = i - r * Kp;
    float v = (r < M && c < K) ? src[(size_t)r * K + c] : 0.0f;
    unsigned short h = f2bf(v);
    hi[i] = h;
    lo[i] = f2bf(v - bf2f(h));
}

// WalT_ext[201][200]: rows 0..199 = Wal^T, row 200 = bal
__global__ __launch_bounds__(256) void build_walt_kernel(
    const float* __restrict__ Wal, const float* __restrict__ bal,
    float* __restrict__ WalT)
{
    int i = blockIdx.x * 256 + threadIdx.x;
    if (i >= 201 * 200) return;
    int j = i / 200, k = i - j * 200;
    WalT[i] = (j < 200) ? Wal[(size_t)k * 200 + j] : bal[k];
}

__global__ __launch_bounds__(256) void sqdiff_reduce_kernel(
    const float* __restrict__ a, const float* __restrict__ b, int n,
    double* __restrict__ acc)
{
    __shared__ float red[256];
    int tid = threadIdx.x;
    float s = 0.0f;
    for (int i = blockIdx.x * 256 + tid; i < n; i += gridDim.x * 256) {
        float d = a[i] - b[i];
        s += d * d;
    }
    red[tid] = s;
    __syncthreads();
    for (int st = 128; st > 0; st >>= 1) {
        if (tid < st) red[tid] += red[tid + st];
        __syncthreads();
    }
    if (tid == 0) atomicAdd(acc, (double)red[0]);
}

__global__ void final_kernel(const double* __restrict__ acc, float* __restrict__ out)
{
    if (threadIdx.x == 0) {
        out[0] = (float)(acc[0] / ((double)BB * EE));
        out[1] = (float)(-acc[1] / ((double)BB * NN));
    }
}

// ---------------------------------------------------------------------------
extern "C" void kernel_launch(void* const* d_in, const int* in_sizes, int n_in,
                              void* d_out, int out_size, void* d_ws, size_t ws_size,
                              hipStream_t stream) {
    const float* pre_emb = (const float*)d_in[0];
    const float* r_emb   = (const float*)d_in[1];
    const float* part    = (const float*)d_in[2];
    const int*   triples = (const int*)d_in[3];
    const float* W1  = (const float*)d_in[6];
    const float* b1  = (const float*)d_in[7];
    const float* W2  = (const float*)d_in[8];
    const float* b2  = (const float*)d_in[9];
    const float* Wa  = (const float*)d_in[10];
    const float* ba  = (const float*)d_in[11];
    const float* Wh1 = (const float*)d_in[12];
    const float* bh1 = (const float*)d_in[13];
    const float* Wh2 = (const float*)d_in[14];
    const float* bh2 = (const float*)d_in[15];
    const float* Wal = (const float*)d_in[16];
    const float* bal = (const float*)d_in[17];
    const float* wih = (const float*)d_in[18];
    const float* whh = (const float*)d_in[19];
    const float* bih = (const float*)d_in[20];
    const float* bhh = (const float*)d_in[21];

    float* out = (float*)d_out;
    double* acc = (double*)d_ws;
    float* wsf = (float*)d_ws;
    size_t off = 4;
    auto alloc = [&](size_t n) { float* p = wsf + off; off += (n + 3) & ~(size_t)3; return p; };

    float* h1     = alloc((size_t)RR * 400);
    float* map    = alloc((size_t)RR * EE);
    float* qrel   = alloc((size_t)BB * EE);
    float* qa     = alloc((size_t)BB * EE);
    float* basep  = alloc((size_t)BB * RR);
    unsigned short* aw_hi = (unsigned short*)alloc((size_t)TT * BB * RR / 2);
    unsigned short* aw_lo = (unsigned short*)alloc((size_t)TT * BB * RR / 2);
    unsigned short* wgi_hi = (unsigned short*)alloc((size_t)NPAD * RR / 2);
    unsigned short* wgi_lo = (unsigned short*)alloc((size_t)NPAD * RR / 2);
    unsigned short* whh_hi = (unsigned short*)alloc((size_t)NPAD * KP / 2);
    unsigned short* whh_lo = (unsigned short*)alloc((size_t)NPAD * KP / 2);
    float* gi_all = alloc((size_t)TT * BB * 3 * EE);
    float* gh     = alloc((size_t)BB * 3 * EE);
    float* h      = alloc((size_t)BB * EE);
    unsigned short* h_hi = (unsigned short*)alloc((size_t)BB * KP / 2);
    unsigned short* h_lo = (unsigned short*)alloc((size_t)BB * KP / 2);
    float* ph1    = alloc((size_t)BB * EE);
    float* pred   = alloc((size_t)BB * EE);
    float* ghid2  = alloc((size_t)BB * EE);
    float* s1h    = alloc((size_t)BB * EE);
    float* WalT   = alloc((size_t)201 * EE);
    unsigned short* u_bf = (unsigned short*)alloc((size_t)BB * KP / 2);

    hipMemsetAsync(acc, 0, 2 * sizeof(double), stream);
    hipMemsetAsync(h, 0, (size_t)BB * EE * sizeof(float), stream);
    hipMemsetAsync(h_hi, 0, (size_t)BB * KP * 2, stream);
    hipMemsetAsync(h_lo, 0, (size_t)BB * KP * 2, stream);
    hipMemsetAsync(wgi_hi, 0, (size_t)NPAD * RR * 2, stream);
    hipMemsetAsync(wgi_lo, 0, (size_t)NPAD * RR * 2, stream);

    dim3 blk(256);
    auto lgrid = [](int M, int N) { return dim3((N + TS_N - 1) / TS_N, (M + TS_M - 1) / TS_M); };

    // whh -> bf16 hi/lo (padded 640 x 224), once
    convert_split_kernel<<<(NPAD * KP + 255) / 256, blk, 0, stream>>>(whh, 3 * EE, EE, NPAD, KP, whh_hi, whh_lo);

    // mapped_rel = lin(lin(r_emb, W1, b1), W2, b2)
    linear_kernel<0,0><<<lgrid(RR, 400), blk, 0, stream>>>(r_emb, nullptr, 0, 0, W1, b1, h1, nullptr, RR, 400, EE, nullptr, 0.f, 0);
    linear_kernel<0,0><<<lgrid(RR, EE), blk, 0, stream>>>(h1, nullptr, 0, 0, W2, b2, map, nullptr, RR, EE, 400, nullptr, 0.f, 0);
    gather_rows_kernel<<<((BB * EE) + 255) / 256, blk, 0, stream>>>(map, triples, 3, 1, qrel, BB, EE);
    // base = (q_rel @ Wa.T + ba) @ mapped_rel.T
    linear_kernel<0,0><<<lgrid(BB, EE), blk, 0, stream>>>(qrel, nullptr, 0, 0, Wa, ba, qa, nullptr, BB, EE, EE, nullptr, 0.f, 0);
    linear_kernel<0,0><<<lgrid(BB, RR), blk, 0, stream>>>(qa, nullptr, 0, 0, map, nullptr, basep, nullptr, BB, RR, EE, nullptr, 0.f, 0);

    // all-t masked softmax -> bf16 hi/lo
    masked_softmax_all_kernel<<<TT * BB, blk, 0, stream>>>(basep, part, aw_hi, aw_lo);
    // Wgi = wih @ map.T (600x480) -> bf16 hi/lo (rows 600..639 stay zero)
    linear_kernel<0,2><<<lgrid(3 * EE, RR), blk, 0, stream>>>(wih, nullptr, 0, 0, map, nullptr, wgi_hi, wgi_lo, 3 * EE, RR, EE, nullptr, 0.f, RR);
    // gi_all = aw_all @ Wgi.T + bih  (8192 x 600, Ks=480) via bf16x3 MFMA
    mfma_linear3_kernel<<<dim3((3 * EE + 63) / 64, TT * BB / 64), blk, 0, stream>>>(
        aw_hi, aw_lo, wgi_hi, wgi_lo, bih, gi_all, TT * BB, 3 * EE, RR);

    // scan: gh = h @ whh.T + bhh (bf16x3 MFMA), then fused combine + h split
    for (int t = 0; t < TT; t++) {
        mfma_linear3_kernel<<<dim3((3 * EE + 63) / 64, BB / 64), blk, 0, stream>>>(
            h_hi, h_lo, whh_hi, whh_lo, bhh, gh, BB, 3 * EE, KP);
        gru_combine_kernel<1><<<((BB * EE) + 255) / 256, blk, 0, stream>>>(
            gi_all + (size_t)t * BB * 3 * EE, gh, h, h, h_hi, h_lo);
    }

    // predicted_hist = 0.1*lin(lin(q_rel,Wh1,bh1),Wh2,bh2) + q_rel
    linear_kernel<0,0><<<lgrid(BB, EE), blk, 0, stream>>>(qrel, nullptr, 0, 0, Wh1, bh1, ph1, nullptr, BB, EE, EE, nullptr, 0.f, 0);
    linear_kernel<1,0><<<lgrid(BB, EE), blk, 0, stream>>>(ph1, nullptr, 0, 0, Wh2, bh2, pred, nullptr, BB, EE, EE, qrel, 0.1f, 0);
    sqdiff_reduce_kernel<<<128, blk, 0, stream>>>(pred, h, BB * EE, acc + 0);

    // gru_hidden2 = gru_cell(q_rel, predicted_hist)  (fp32; reuse gi_all/gh)
    linear_kernel<0,0><<<lgrid(BB, 3 * EE), blk, 0, stream>>>(qrel, nullptr, 0, 0, wih, bih, gi_all, nullptr, BB, 3 * EE, EE, nullptr, 0.f, 0);
    linear_kernel<0,0><<<lgrid(BB, 3 * EE), blk, 0, stream>>>(pred, nullptr, 0, 0, whh, bhh, gh, nullptr, BB, 3 * EE, EE, nullptr, 0.f, 0);
    gru_combine_kernel<0><<<((BB * EE) + 255) / 256, blk, 0, stream>>>(gi_all, gh, pred, ghid2, nullptr, nullptr);

    // s1h = (pre_emb[sub] @ Wal.T + bal) * gru_hidden2  (fp32)
    linear_kernel<2,0><<<lgrid(BB, EE), blk, 0, stream>>>(pre_emb, triples, 3, 0, Wal, bal, s1h, nullptr, BB, EE, EE, ghid2, 0.f, 0);
    // u = s1h @ [Wal^T ; bal] -> bf16 [1024][224], col 200 = s1h.bal
    build_walt_kernel<<<(201 * 200 + 255) / 256, blk, 0, stream>>>(Wal, bal, WalT);
    linear_kernel<0,1><<<lgrid(BB, KP), blk, 0, stream>>>(s1h, nullptr, 0, 0, WalT, nullptr, u_bf, nullptr, BB, 201, EE, nullptr, 0.f, KP);

    // score + path loss
    score_mfma2_kernel<<<NN / 64, blk, 0, stream>>>(u_bf, pre_emb, triples, out + 2, acc + 1);
    final_kernel<<<1, 64, 0, stream>>>(acc, out);
}